// Round 6
// baseline (229.620 us; speedup 1.0000x reference)
//
#include <hip/hip_runtime.h>
#include <hip/hip_bf16.h>
#include <stdint.h>

typedef float f32x16 __attribute__((ext_vector_type(16)));
typedef float f32x4  __attribute__((ext_vector_type(4)));
typedef short s16x8  __attribute__((ext_vector_type(8)));
typedef unsigned int u32x4 __attribute__((ext_vector_type(4)));

#define HWSZ   4096
#define NBATCH 4
#define LOG2E  1.44269504088896340736f

__device__ __forceinline__ unsigned short f2bf(float f) {
    unsigned u = __builtin_bit_cast(unsigned, f);
    u += 0x7FFFu + ((u >> 16) & 1u);          // RTNE
    return (unsigned short)(u >> 16);
}
__device__ __forceinline__ unsigned cvt_pk_bf16(float lo, float hi) {
    __hip_bfloat162 h = __float22bfloat162_rn(make_float2(lo, hi));
    return *reinterpret_cast<unsigned*>(&h);   // v_cvt_pk_bf16_f32
}

// ---------------- Kernel 1: MFMA projections ----------------
// xq = x@W1 + b1 -> d_out (f32 residual) + xq_bf (bf16, PRE-SCALED by log2e: K-only)
// yk = y@W2 + b2 -> yk_bf (bf16) + ykT_bf (bf16 transposed)
__global__ __launch_bounds__(256, 1) void proj_kernel(
    const float* __restrict__ x, const float* __restrict__ y,
    const float* __restrict__ W1, const float* __restrict__ b1,
    const float* __restrict__ W2, const float* __restrict__ b2,
    float* __restrict__ xq_f32,
    unsigned short* __restrict__ xq_bf,
    unsigned short* __restrict__ yk_bf,
    unsigned short* __restrict__ ykT_bf)
{
    __shared__ unsigned short Xlds[64][136];
    __shared__ unsigned short Ylds[64][136];
    __shared__ unsigned short Tlds[128][72];

    const int t    = threadIdx.x;
    const int lane = t & 63;
    const int w    = t >> 6;
    const int l31  = lane & 31;
    const int g    = lane >> 5;
    const int r0   = blockIdx.x * 64;
    const int b    = r0 >> 12;
    const int j0   = r0 & (HWSZ - 1);

    #pragma unroll
    for (int i = 0; i < 8; ++i) {
        int li = t + 256 * i;
        int row = li >> 5, c = (li & 31) * 4;
        float4 vx = *(const float4*)(x + (size_t)(r0 + row) * 128 + c);
        float4 vy = *(const float4*)(y + (size_t)(r0 + row) * 128 + c);
        *(uint2*)&Xlds[row][c] = make_uint2(cvt_pk_bf16(vx.x, vx.y), cvt_pk_bf16(vx.z, vx.w));
        *(uint2*)&Ylds[row][c] = make_uint2(cvt_pk_bf16(vy.x, vy.y), cvt_pk_bf16(vy.z, vy.w));
    }
    __syncthreads();

    const int m  = w >> 1;
    const int fh = w & 1;
    const float* Wm = m ? W2 : W1;
    const float* bm = m ? b2 : b1;
    const unsigned short* A0 = m ? &Ylds[0][0] : &Xlds[0][0];

    f32x16 acc[2][2];
    #pragma unroll
    for (int i = 0; i < 16; ++i) {
        acc[0][0][i] = 0.f; acc[0][1][i] = 0.f;
        acc[1][0][i] = 0.f; acc[1][1][i] = 0.f;
    }

    #pragma unroll
    for (int ks = 0; ks < 8; ++ks) {
        s16x8 bfr[2];
        #pragma unroll
        for (int ft = 0; ft < 2; ++ft) {
            const float* wp = Wm + (size_t)(ks * 16 + g * 8) * 128 + fh * 64 + ft * 32 + l31;
            #pragma unroll
            for (int i = 0; i < 8; ++i)
                bfr[ft][i] = (short)f2bf(wp[(size_t)i * 128]);
        }
        #pragma unroll
        for (int rt = 0; rt < 2; ++rt) {
            s16x8 af = *(const s16x8*)(A0 + (size_t)(rt * 32 + l31) * 136 + ks * 16 + g * 8);
            acc[rt][0] = __builtin_amdgcn_mfma_f32_32x32x16_bf16(af, bfr[0], acc[rt][0], 0, 0, 0);
            acc[rt][1] = __builtin_amdgcn_mfma_f32_32x32x16_bf16(af, bfr[1], acc[rt][1], 0, 0, 0);
        }
    }

    const float bias_v[2] = { bm[fh * 64 + l31], bm[fh * 64 + 32 + l31] };

    if (m == 0) {
        #pragma unroll
        for (int rt = 0; rt < 2; ++rt)
        #pragma unroll
        for (int ft = 0; ft < 2; ++ft) {
            int f = fh * 64 + ft * 32 + l31;
            #pragma unroll
            for (int r = 0; r < 16; ++r) {
                int row = rt * 32 + (r & 3) + 8 * (r >> 2) + 4 * g;
                float v = acc[rt][ft][r] + bias_v[ft];
                size_t o = (size_t)(r0 + row) * 128 + f;
                xq_f32[o] = v;
                xq_bf[o]  = f2bf(v * LOG2E);      // K pre-scaled for exp2 sigmoid
            }
        }
    } else {
        #pragma unroll
        for (int rt = 0; rt < 2; ++rt)
        #pragma unroll
        for (int ft = 0; ft < 2; ++ft) {
            int f = fh * 64 + ft * 32 + l31;
            #pragma unroll
            for (int rg = 0; rg < 4; ++rg) {
                float p0 = acc[rt][ft][4 * rg + 0] + bias_v[ft];
                float p1 = acc[rt][ft][4 * rg + 1] + bias_v[ft];
                float p2 = acc[rt][ft][4 * rg + 2] + bias_v[ft];
                float p3 = acc[rt][ft][4 * rg + 3] + bias_v[ft];
                int jb = rt * 32 + 8 * rg + 4 * g;
                *(uint2*)&Tlds[f][jb] = make_uint2(cvt_pk_bf16(p0, p1), cvt_pk_bf16(p2, p3));
                size_t o = (size_t)(r0 + jb) * 128 + f;
                yk_bf[o]       = f2bf(p0);
                yk_bf[o + 128] = f2bf(p1);
                yk_bf[o + 256] = f2bf(p2);
                yk_bf[o + 384] = f2bf(p3);
            }
        }
    }
    __syncthreads();

    {
        int f  = t >> 1;
        int jh = (t & 1) * 32;
        unsigned short* dst = ykT_bf + ((size_t)(b * 128 + f)) * HWSZ + j0 + jh;
        #pragma unroll
        for (int c = 0; c < 4; ++c)
            *(s16x8*)(dst + c * 8) = *(const s16x8*)&Tlds[f][jh + c * 8];
    }
}

// ---------------- shared attention LDS geometry ----------------
#define KT_STR   136
#define VT_STR   72
#define KT_BYTES (64 * KT_STR * 2)
#define VT_BYTES (128 * VT_STR * 2)
#define BUF_BYTES (KT_BYTES + VT_BYTES)

// ---------------- Kernel 2a: QBLK=128, K-direct, V-only LDS ----------------
// LDS = V double-buffer only (36864 B) -> 4 WG/CU capacity. K MFMA A-frags are
// qt-independent and read directly from global (L1/L2-resident). Grid =
// 128 q-WGs x SPLITS j-splits; partials reduced by reduceN_kernel.
template<int SPLITS>
__global__ __launch_bounds__(256, 4) void attn128v2_kernel(
    const unsigned short* __restrict__ Kbf,   // xq_bf (log2e-scaled) [b][j][128]
    const unsigned short* __restrict__ Qbf,   // yk_bf  [b][q][128]
    const unsigned short* __restrict__ Vtbf,  // ykT_bf [b][128][4096]
    float* __restrict__ outp)                 // partials base (SPLITS x NELEM)
{
    __shared__ __align__(16) unsigned short Vlds[2][128 * VT_STR];  // 36864 B

    const int t    = threadIdx.x;
    const int lane = t & 63;
    const int qt   = t >> 6;
    const int l31  = lane & 31;
    const int g    = lane >> 5;

    const int split  = blockIdx.x >> 7;
    const int r      = blockIdx.x & 127;
    const int b      = r >> 5;
    const int qb     = (r & 31) * 128;
    const int jBegin = split * (HWSZ / SPLITS);
    const int nt     = (HWSZ / SPLITS) / 64;

    s16x8 qfrag[8];
    {
        const unsigned short* qp =
            Qbf + (((size_t)(b * HWSZ + qb + 32 * qt + l31)) << 7) + g * 8;
        #pragma unroll
        for (int fs = 0; fs < 8; ++fs)
            qfrag[fs] = *(const s16x8*)(qp + fs * 16);
    }

    f32x16 acc[4];
    #pragma unroll
    for (int ft = 0; ft < 4; ++ft)
        #pragma unroll
        for (int i = 0; i < 16; ++i) acc[ft][i] = 0.f;

    const unsigned short* Kbase = Kbf  + (((size_t)b * HWSZ) << 7);
    const unsigned short* Vbase = Vtbf + (((size_t)b) << 7) * HWSZ;

    // K direct per-lane pointer: row jBegin + l31, col g*8 (+ jt*32 rows, + fs*16 cols)
    const unsigned short* kIt = Kbase + (size_t)(jBegin + l31) * 128 + g * 8;

    const unsigned short* vSrc = Vbase + (size_t)(t >> 3) * HWSZ + jBegin + (t & 7) * 8;
    const int vDst = (t >> 3) * VT_STR + (t & 7) * 8;

    {   // prologue: stage V tile 0 into buf 0
        #pragma unroll
        for (int i = 0; i < 4; ++i)
            *(s16x8*)(&Vlds[0][0] + vDst + i * 32 * VT_STR) =
                *(const s16x8*)(vSrc + (size_t)i * 32 * HWSZ);
    }
    __syncthreads();

    int c = 0;
    for (int it = 0; it < nt; ++it) {
        const bool pre = (it + 1 < nt);
        s16x8 vr[4];
        if (pre) {                       // issue-early V loads for tile it+1
            vSrc += 64;
            #pragma unroll
            for (int i = 0; i < 4; ++i)
                vr[i] = *(const s16x8*)(vSrc + (size_t)i * 32 * HWSZ);
        }

        const unsigned short* Vl = &Vlds[c][0];

        #pragma unroll
        for (int jt = 0; jt < 2; ++jt) {
            // ---- K frags direct from global ----
            const unsigned short* kp = kIt + jt * 32 * 128;
            s16x8 kf[8];
            #pragma unroll
            for (int fs = 0; fs < 8; ++fs)
                kf[fs] = *(const s16x8*)(kp + fs * 16);

            // ---- QK subtile: S'[32j][32q], dual-chain ----
            f32x16 sa, sb;
            #pragma unroll
            for (int i = 0; i < 16; ++i) { sa[i] = 0.f; sb[i] = 0.f; }
            __builtin_amdgcn_s_setprio(1);
            #pragma unroll
            for (int fs = 0; fs < 4; ++fs) {
                sa = __builtin_amdgcn_mfma_f32_32x32x16_bf16(kf[fs], qfrag[fs], sa, 0, 0, 0);
                sb = __builtin_amdgcn_mfma_f32_32x32x16_bf16(kf[fs + 4], qfrag[fs + 4], sb, 0, 0, 0);
            }
            __builtin_amdgcn_s_setprio(0);

            // ---- sigmoid via exp2 (K pre-scaled) + cvt_pk pack ----
            unsigned W0[4], W1[4];
            #pragma unroll
            for (int rg = 0; rg < 4; ++rg) {
                float s0 = sa[4 * rg + 0] + sb[4 * rg + 0];
                float s1 = sa[4 * rg + 1] + sb[4 * rg + 1];
                float s2v = sa[4 * rg + 2] + sb[4 * rg + 2];
                float s3 = sa[4 * rg + 3] + sb[4 * rg + 3];
                float p0 = __builtin_amdgcn_rcpf(1.f + __builtin_amdgcn_exp2f(-s0));
                float p1 = __builtin_amdgcn_rcpf(1.f + __builtin_amdgcn_exp2f(-s1));
                float p2 = __builtin_amdgcn_rcpf(1.f + __builtin_amdgcn_exp2f(-s2v));
                float p3 = __builtin_amdgcn_rcpf(1.f + __builtin_amdgcn_exp2f(-s3));
                W0[rg] = cvt_pk_bf16(p0, p1);
                W1[rg] = cvt_pk_bf16(p2, p3);
            }

            // ---- PV: A-frag via lane^32 exchange; ks = 2*jt + s2 ----
            #pragma unroll
            for (int s2 = 0; s2 < 2; ++s2) {
                unsigned o0 = g ? W0[2 * s2 + 1] : W0[2 * s2];
                unsigned o1 = g ? W1[2 * s2 + 1] : W1[2 * s2];
                unsigned t0 = g ? W0[2 * s2]     : W0[2 * s2 + 1];
                unsigned t1 = g ? W1[2 * s2]     : W1[2 * s2 + 1];
                unsigned r0 = __shfl_xor(t0, 32, 64);
                unsigned r1 = __shfl_xor(t1, 32, 64);
                u32x4 pw;
                pw[0] = g ? r0 : o0;
                pw[1] = g ? r1 : o1;
                pw[2] = g ? o0 : r0;
                pw[3] = g ? o1 : r1;
                s16x8 pf = __builtin_bit_cast(s16x8, pw);
                const int ks = 2 * jt + s2;
                __builtin_amdgcn_s_setprio(1);
                #pragma unroll
                for (int ft = 0; ft < 4; ++ft) {
                    s16x8 vf = *(const s16x8*)(Vl + (size_t)(32 * ft + l31) * VT_STR + ks * 16 + g * 8);
                    acc[ft] = __builtin_amdgcn_mfma_f32_32x32x16_bf16(pf, vf, acc[ft], 0, 0, 0);
                }
                __builtin_amdgcn_s_setprio(0);
            }
        }
        kIt += 64 * 128;

        if (pre) {                       // write-late into other buffer
            #pragma unroll
            for (int i = 0; i < 4; ++i)
                *(s16x8*)(&Vlds[c ^ 1][0] + vDst + i * 32 * VT_STR) = vr[i];
        }
        __syncthreads();
        c ^= 1;
    }

    // ---- epilogue: direct store of wave-private 32q x 128f partial ----
    float* op = outp + (size_t)split * ((size_t)NBATCH * HWSZ * 128);
    #pragma unroll
    for (int ft = 0; ft < 4; ++ft)
    #pragma unroll
    for (int r2 = 0; r2 < 16; ++r2) {
        int row = (r2 & 3) + 8 * (r2 >> 2) + 4 * g;
        int q = qb + 32 * qt + row;
        size_t o = (((size_t)(b * HWSZ + q)) << 7) + 32 * ft + l31;
        op[o] = acc[ft][r2];
    }
}

// ---------------- Kernel 2b: QBLK=64 fallback (2-split / no-split) ----------------
template<bool SPLIT>
__global__ __launch_bounds__(256, 2) void attn_kernel(
    const unsigned short* __restrict__ Kbf,
    const unsigned short* __restrict__ Qbf,
    const unsigned short* __restrict__ Vtbf,
    const float* __restrict__ resid,
    float* __restrict__ outp)
{
    __shared__ __align__(16) char smem[2 * BUF_BYTES];

    const int t    = threadIdx.x;
    const int lane = t & 63;
    const int w    = t >> 6;
    const int qt   = w & 1;
    const int jt   = w >> 1;
    const int l31  = lane & 31;
    const int g    = lane >> 5;

    int bid = blockIdx.x;
    int half = 0;
    if (SPLIT) { half = bid >> 8; bid &= 255; }
    const int b      = bid >> 6;
    const int qb     = (bid & 63) * 64;
    const int jBegin = half * (HWSZ / 2);
    const int nt     = (SPLIT ? HWSZ / 2 : HWSZ) / 64;

    s16x8 qfrag[8];
    {
        const unsigned short* qp =
            Qbf + (((size_t)(b * HWSZ + qb + 32 * qt + l31)) << 7) + g * 8;
        #pragma unroll
        for (int fs = 0; fs < 8; ++fs)
            qfrag[fs] = *(const s16x8*)(qp + fs * 16);
    }

    f32x16 acc[4];
    #pragma unroll
    for (int ft = 0; ft < 4; ++ft)
        #pragma unroll
        for (int i = 0; i < 16; ++i) acc[ft][i] = 0.f;

    const unsigned short* Kbase = Kbf  + (((size_t)b * HWSZ) << 7);
    const unsigned short* Vbase = Vtbf + (((size_t)b) << 7) * HWSZ;

    const unsigned short* kSrc = Kbase + (size_t)(jBegin + (t >> 4)) * 128 + (t & 15) * 8;
    const unsigned short* vSrc = Vbase + (size_t)(t >> 3) * HWSZ + jBegin + (t & 7) * 8;
    const int kDst = (t >> 4) * KT_STR + (t & 15) * 8;
    const int vDst = (t >> 3) * VT_STR + (t & 7) * 8;

    {
        unsigned short* Kl = (unsigned short*)smem;
        unsigned short* Vl = (unsigned short*)(smem + KT_BYTES);
        #pragma unroll
        for (int i = 0; i < 4; ++i)
            *(s16x8*)(Kl + kDst + i * 16 * KT_STR) = *(const s16x8*)(kSrc + (size_t)i * 2048);
        #pragma unroll
        for (int i = 0; i < 4; ++i)
            *(s16x8*)(Vl + vDst + i * 32 * VT_STR) = *(const s16x8*)(vSrc + (size_t)i * 32 * HWSZ);
    }
    __syncthreads();

    int c = 0;
    for (int it = 0; it < nt; ++it) {
        const bool pre = (it + 1 < nt);
        s16x8 kr[4], vr[4];
        if (pre) {
            kSrc += 64 * 128;
            vSrc += 64;
            #pragma unroll
            for (int i = 0; i < 4; ++i)
                kr[i] = *(const s16x8*)(kSrc + (size_t)i * 2048);
            #pragma unroll
            for (int i = 0; i < 4; ++i)
                vr[i] = *(const s16x8*)(vSrc + (size_t)i * 32 * HWSZ);
        }

        const unsigned short* Kl = (const unsigned short*)(smem + c * BUF_BYTES);
        const unsigned short* Vl = (const unsigned short*)(smem + c * BUF_BYTES + KT_BYTES);

        f32x16 sa, sb;
        #pragma unroll
        for (int i = 0; i < 16; ++i) { sa[i] = 0.f; sb[i] = 0.f; }
        const unsigned short* Krow = Kl + (size_t)(32 * jt + l31) * KT_STR + g * 8;
        __builtin_amdgcn_s_setprio(1);
        #pragma unroll
        for (int fs = 0; fs < 4; ++fs) {
            sa = __builtin_amdgcn_mfma_f32_32x32x16_bf16(
                     *(const s16x8*)(Krow + fs * 16), qfrag[fs], sa, 0, 0, 0);
            sb = __builtin_amdgcn_mfma_f32_32x32x16_bf16(
                     *(const s16x8*)(Krow + (fs + 4) * 16), qfrag[fs + 4], sb, 0, 0, 0);
        }
        __builtin_amdgcn_s_setprio(0);

        unsigned W0[4], W1[4];
        #pragma unroll
        for (int rg = 0; rg < 4; ++rg) {
            float s0 = sa[4 * rg + 0] + sb[4 * rg + 0];
            float s1 = sa[4 * rg + 1] + sb[4 * rg + 1];
            float s2v = sa[4 * rg + 2] + sb[4 * rg + 2];
            float s3 = sa[4 * rg + 3] + sb[4 * rg + 3];
            float p0 = __builtin_amdgcn_rcpf(1.f + __builtin_amdgcn_exp2f(-s0));
            float p1 = __builtin_amdgcn_rcpf(1.f + __builtin_amdgcn_exp2f(-s1));
            float p2 = __builtin_amdgcn_rcpf(1.f + __builtin_amdgcn_exp2f(-s2v));
            float p3 = __builtin_amdgcn_rcpf(1.f + __builtin_amdgcn_exp2f(-s3));
            W0[rg] = cvt_pk_bf16(p0, p1);
            W1[rg] = cvt_pk_bf16(p2, p3);
        }

        #pragma unroll
        for (int s2 = 0; s2 < 2; ++s2) {
            unsigned o0 = g ? W0[2 * s2 + 1] : W0[2 * s2];
            unsigned o1 = g ? W1[2 * s2 + 1] : W1[2 * s2];
            unsigned t0 = g ? W0[2 * s2]     : W0[2 * s2 + 1];
            unsigned t1 = g ? W1[2 * s2]     : W1[2 * s2 + 1];
            unsigned r0 = __shfl_xor(t0, 32, 64);
            unsigned r1 = __shfl_xor(t1, 32, 64);
            u32x4 pw;
            pw[0] = g ? r0 : o0;
            pw[1] = g ? r1 : o1;
            pw[2] = g ? o0 : r0;
            pw[3] = g ? o1 : r1;
            s16x8 pf = __builtin_bit_cast(s16x8, pw);
            const int ks = 2 * jt + s2;
            __builtin_amdgcn_s_setprio(1);
            #pragma unroll
            for (int ft = 0; ft < 4; ++ft) {
                s16x8 vf = *(const s16x8*)(Vl + (size_t)(32 * ft + l31) * VT_STR + ks * 16 + g * 8);
                acc[ft] = __builtin_amdgcn_mfma_f32_32x32x16_bf16(pf, vf, acc[ft], 0, 0, 0);
            }
            __builtin_amdgcn_s_setprio(0);
        }

        if (pre) {
            unsigned short* Kd = (unsigned short*)(smem + (c ^ 1) * BUF_BYTES);
            unsigned short* Vd = (unsigned short*)(smem + (c ^ 1) * BUF_BYTES + KT_BYTES);
            #pragma unroll
            for (int i = 0; i < 4; ++i)
                *(s16x8*)(Kd + kDst + i * 16 * KT_STR) = kr[i];
            #pragma unroll
            for (int i = 0; i < 4; ++i)
                *(s16x8*)(Vd + vDst + i * 32 * VT_STR) = vr[i];
        }
        __syncthreads();
        c ^= 1;
    }

    float* red = (float*)smem;
    if (jt == 1) {
        #pragma unroll
        for (int ft = 0; ft < 4; ++ft)
        #pragma unroll
        for (int r = 0; r < 16; ++r) {
            int row = (r & 3) + 8 * (r >> 2) + 4 * g;
            red[qt * 4096 + row * 128 + 32 * ft + l31] = acc[ft][r];
        }
    }
    __syncthreads();
    if (jt == 0) {
        float* op = outp + (SPLIT ? (size_t)half * ((size_t)NBATCH * HWSZ * 128) : 0);
        #pragma unroll
        for (int ft = 0; ft < 4; ++ft)
        #pragma unroll
        for (int r = 0; r < 16; ++r) {
            int row = (r & 3) + 8 * (r >> 2) + 4 * g;
            float v = acc[ft][r] + red[qt * 4096 + row * 128 + 32 * ft + l31];
            int q = qb + 32 * qt + row;
            size_t o = (((size_t)(b * HWSZ + q)) << 7) + 32 * ft + l31;
            if (SPLIT) op[o] = v;
            else       op[o] = v + resid[o];
        }
    }
}

// ---------------- Kernel 3: partial reduce + residual ----------------
__global__ __launch_bounds__(256, 1) void reduce2_kernel(
    const float* __restrict__ p0, const float* __restrict__ p1, float* outp)
{
    int i = blockIdx.x * 256 + threadIdx.x;
    f32x4 a = ((const f32x4*)p0)[i];
    f32x4 b = ((const f32x4*)p1)[i];
    f32x4 c = ((f32x4*)outp)[i];
    ((f32x4*)outp)[i] = a + b + c;
}

template<int S>
__global__ __launch_bounds__(256, 1) void reduceN_kernel(
    const float* __restrict__ parts, float* __restrict__ outp)
{
    const size_t N4 = (size_t)NBATCH * HWSZ * 128 / 4;
    size_t i = (size_t)blockIdx.x * 256 + threadIdx.x;
    f32x4 s = ((f32x4*)outp)[i];          // xq residual
    #pragma unroll
    for (int k = 0; k < S; ++k)
        s += ((const f32x4*)parts)[i + (size_t)k * N4];
    ((f32x4*)outp)[i] = s;
}

extern "C" void kernel_launch(void* const* d_in, const int* in_sizes, int n_in,
                              void* d_out, int out_size, void* d_ws, size_t ws_size,
                              hipStream_t stream) {
    const float* x  = (const float*)d_in[0];
    const float* y  = (const float*)d_in[1];
    const float* W1 = (const float*)d_in[2];
    const float* b1 = (const float*)d_in[3];
    const float* W2 = (const float*)d_in[4];
    const float* b2 = (const float*)d_in[5];
    float* out = (float*)d_out;

    const size_t NELEM = (size_t)NBATCH * HWSZ * 128;   // 2,097,152
    unsigned short* xq_bf  = (unsigned short*)d_ws;
    unsigned short* yk_bf  = xq_bf + NELEM;
    unsigned short* ykT_bf = yk_bf + NELEM;
    float* part = (float*)(ykT_bf + NELEM);

    proj_kernel<<<(int)(NBATCH * HWSZ / 64), 256, 0, stream>>>(
        x, y, W1, b1, W2, b2, out, xq_bf, yk_bf, ykT_bf);

    if (ws_size >= NELEM * (6 + 32)) {               // 79.7 MB: QBLK=128, 8-split
        attn128v2_kernel<8><<<1024, 256, 0, stream>>>(xq_bf, yk_bf, ykT_bf, part);
        reduceN_kernel<8><<<(int)(NELEM / 1024), 256, 0, stream>>>(part, out);
    } else if (ws_size >= NELEM * (6 + 16)) {        // 46.1 MB: QBLK=128, 4-split
        attn128v2_kernel<4><<<512, 256, 0, stream>>>(xq_bf, yk_bf, ykT_bf, part);
        reduceN_kernel<4><<<(int)(NELEM / 1024), 256, 0, stream>>>(part, out);
    } else if (ws_size >= NELEM * (6 + 8)) {         // 29.4 MB: QBLK=64, 2-split
        attn_kernel<true><<<512, 256, 0, stream>>>(xq_bf, yk_bf, ykT_bf, out, part);
        reduce2_kernel<<<(int)(NELEM / 1024), 256, 0, stream>>>(part, part + NELEM, out);
    } else {
        attn_kernel<false><<<256, 256, 0, stream>>>(xq_bf, yk_bf, ykT_bf, out, out);
    }
}

// Round 7
// 105.131 us; speedup vs baseline: 2.1841x; 2.1841x over previous
//
#include <hip/hip_runtime.h>
#include <hip/hip_bf16.h>
#include <stdint.h>

typedef float f32x16 __attribute__((ext_vector_type(16)));
typedef float f32x4  __attribute__((ext_vector_type(4)));
typedef short s16x8  __attribute__((ext_vector_type(8)));
typedef unsigned int u32x4 __attribute__((ext_vector_type(4)));

#define HWSZ   4096
#define NBATCH 4
#define LOG2E  1.44269504088896340736f

__device__ __forceinline__ unsigned short f2bf(float f) {
    unsigned u = __builtin_bit_cast(unsigned, f);
    u += 0x7FFFu + ((u >> 16) & 1u);          // RTNE
    return (unsigned short)(u >> 16);
}
__device__ __forceinline__ unsigned cvt_pk_bf16(float lo, float hi) {
    __hip_bfloat162 h = __float22bfloat162_rn(make_float2(lo, hi));
    return *reinterpret_cast<unsigned*>(&h);   // v_cvt_pk_bf16_f32
}

// ---------------- Kernel 1: MFMA projections ----------------
// xq = x@W1 + b1 -> d_out (f32 residual) + xq_bf (bf16, PRE-SCALED by log2e: K-only)
// yk = y@W2 + b2 -> yk_bf (bf16) + ykT_bf (bf16 transposed)
__global__ __launch_bounds__(256, 1) void proj_kernel(
    const float* __restrict__ x, const float* __restrict__ y,
    const float* __restrict__ W1, const float* __restrict__ b1,
    const float* __restrict__ W2, const float* __restrict__ b2,
    float* __restrict__ xq_f32,
    unsigned short* __restrict__ xq_bf,
    unsigned short* __restrict__ yk_bf,
    unsigned short* __restrict__ ykT_bf)
{
    __shared__ unsigned short Xlds[64][136];
    __shared__ unsigned short Ylds[64][136];
    __shared__ unsigned short Tlds[128][72];

    const int t    = threadIdx.x;
    const int lane = t & 63;
    const int w    = t >> 6;
    const int l31  = lane & 31;
    const int g    = lane >> 5;
    const int r0   = blockIdx.x * 64;
    const int b    = r0 >> 12;
    const int j0   = r0 & (HWSZ - 1);

    #pragma unroll
    for (int i = 0; i < 8; ++i) {
        int li = t + 256 * i;
        int row = li >> 5, c = (li & 31) * 4;
        float4 vx = *(const float4*)(x + (size_t)(r0 + row) * 128 + c);
        float4 vy = *(const float4*)(y + (size_t)(r0 + row) * 128 + c);
        *(uint2*)&Xlds[row][c] = make_uint2(cvt_pk_bf16(vx.x, vx.y), cvt_pk_bf16(vx.z, vx.w));
        *(uint2*)&Ylds[row][c] = make_uint2(cvt_pk_bf16(vy.x, vy.y), cvt_pk_bf16(vy.z, vy.w));
    }
    __syncthreads();

    const int m  = w >> 1;
    const int fh = w & 1;
    const float* Wm = m ? W2 : W1;
    const float* bm = m ? b2 : b1;
    const unsigned short* A0 = m ? &Ylds[0][0] : &Xlds[0][0];

    f32x16 acc[2][2];
    #pragma unroll
    for (int i = 0; i < 16; ++i) {
        acc[0][0][i] = 0.f; acc[0][1][i] = 0.f;
        acc[1][0][i] = 0.f; acc[1][1][i] = 0.f;
    }

    #pragma unroll
    for (int ks = 0; ks < 8; ++ks) {
        s16x8 bfr[2];
        #pragma unroll
        for (int ft = 0; ft < 2; ++ft) {
            const float* wp = Wm + (size_t)(ks * 16 + g * 8) * 128 + fh * 64 + ft * 32 + l31;
            #pragma unroll
            for (int i = 0; i < 8; ++i)
                bfr[ft][i] = (short)f2bf(wp[(size_t)i * 128]);
        }
        #pragma unroll
        for (int rt = 0; rt < 2; ++rt) {
            s16x8 af = *(const s16x8*)(A0 + (size_t)(rt * 32 + l31) * 136 + ks * 16 + g * 8);
            acc[rt][0] = __builtin_amdgcn_mfma_f32_32x32x16_bf16(af, bfr[0], acc[rt][0], 0, 0, 0);
            acc[rt][1] = __builtin_amdgcn_mfma_f32_32x32x16_bf16(af, bfr[1], acc[rt][1], 0, 0, 0);
        }
    }

    const float bias_v[2] = { bm[fh * 64 + l31], bm[fh * 64 + 32 + l31] };

    if (m == 0) {
        #pragma unroll
        for (int rt = 0; rt < 2; ++rt)
        #pragma unroll
        for (int ft = 0; ft < 2; ++ft) {
            int f = fh * 64 + ft * 32 + l31;
            #pragma unroll
            for (int r = 0; r < 16; ++r) {
                int row = rt * 32 + (r & 3) + 8 * (r >> 2) + 4 * g;
                float v = acc[rt][ft][r] + bias_v[ft];
                size_t o = (size_t)(r0 + row) * 128 + f;
                xq_f32[o] = v;
                xq_bf[o]  = f2bf(v * LOG2E);      // K pre-scaled for exp2 sigmoid
            }
        }
    } else {
        #pragma unroll
        for (int rt = 0; rt < 2; ++rt)
        #pragma unroll
        for (int ft = 0; ft < 2; ++ft) {
            int f = fh * 64 + ft * 32 + l31;
            #pragma unroll
            for (int rg = 0; rg < 4; ++rg) {
                float p0 = acc[rt][ft][4 * rg + 0] + bias_v[ft];
                float p1 = acc[rt][ft][4 * rg + 1] + bias_v[ft];
                float p2 = acc[rt][ft][4 * rg + 2] + bias_v[ft];
                float p3 = acc[rt][ft][4 * rg + 3] + bias_v[ft];
                int jb = rt * 32 + 8 * rg + 4 * g;
                *(uint2*)&Tlds[f][jb] = make_uint2(cvt_pk_bf16(p0, p1), cvt_pk_bf16(p2, p3));
                size_t o = (size_t)(r0 + jb) * 128 + f;
                yk_bf[o]       = f2bf(p0);
                yk_bf[o + 128] = f2bf(p1);
                yk_bf[o + 256] = f2bf(p2);
                yk_bf[o + 384] = f2bf(p3);
            }
        }
    }
    __syncthreads();

    {
        int f  = t >> 1;
        int jh = (t & 1) * 32;
        unsigned short* dst = ykT_bf + ((size_t)(b * 128 + f)) * HWSZ + j0 + jh;
        #pragma unroll
        for (int c = 0; c < 4; ++c)
            *(s16x8*)(dst + c * 8) = *(const s16x8*)&Tlds[f][jh + c * 8];
    }
}

// ---------------- shared attention LDS geometry ----------------
#define KT_STR   136
#define VT_STR   72
#define KT_BYTES (64 * KT_STR * 2)
#define VT_BYTES (128 * VT_STR * 2)
#define BUF_BYTES (KT_BYTES + VT_BYTES)

// ---------------- Kernel 2a: QBLK=128, K-direct, V-only LDS ----------------
// LDS = V double-buffer only (36864 B). K MFMA A-frags are qt-independent and
// read directly from global (L1/L2-resident). __launch_bounds__(256,2): cap 256
// regs (NO spill — (256,4) caused catastrophic scratch traffic in R6); natural
// allocation ~96 VGPR + 64 AGPR = 160 -> 3 waves/SIMD.
template<int SPLITS>
__global__ __launch_bounds__(256, 2) void attn128v2_kernel(
    const unsigned short* __restrict__ Kbf,   // xq_bf (log2e-scaled) [b][j][128]
    const unsigned short* __restrict__ Qbf,   // yk_bf  [b][q][128]
    const unsigned short* __restrict__ Vtbf,  // ykT_bf [b][128][4096]
    float* __restrict__ outp)                 // partials base (SPLITS x NELEM)
{
    __shared__ __align__(16) unsigned short Vlds[2][128 * VT_STR];  // 36864 B

    const int t    = threadIdx.x;
    const int lane = t & 63;
    const int qt   = t >> 6;
    const int l31  = lane & 31;
    const int g    = lane >> 5;

    const int split  = blockIdx.x >> 7;
    const int r      = blockIdx.x & 127;
    const int b      = r >> 5;
    const int qb     = (r & 31) * 128;
    const int jBegin = split * (HWSZ / SPLITS);
    const int nt     = (HWSZ / SPLITS) / 64;

    s16x8 qfrag[8];
    {
        const unsigned short* qp =
            Qbf + (((size_t)(b * HWSZ + qb + 32 * qt + l31)) << 7) + g * 8;
        #pragma unroll
        for (int fs = 0; fs < 8; ++fs)
            qfrag[fs] = *(const s16x8*)(qp + fs * 16);
    }

    f32x16 acc[4];
    #pragma unroll
    for (int ft = 0; ft < 4; ++ft)
        #pragma unroll
        for (int i = 0; i < 16; ++i) acc[ft][i] = 0.f;

    const unsigned short* Kbase = Kbf  + (((size_t)b * HWSZ) << 7);
    const unsigned short* Vbase = Vtbf + (((size_t)b) << 7) * HWSZ;

    // K direct per-lane pointer: row jBegin + l31, col g*8 (+ jt*32 rows, + fs*16 cols)
    const unsigned short* kIt = Kbase + (size_t)(jBegin + l31) * 128 + g * 8;

    const unsigned short* vSrc = Vbase + (size_t)(t >> 3) * HWSZ + jBegin + (t & 7) * 8;
    const int vDst = (t >> 3) * VT_STR + (t & 7) * 8;

    {   // prologue: stage V tile 0 into buf 0
        #pragma unroll
        for (int i = 0; i < 4; ++i)
            *(s16x8*)(&Vlds[0][0] + vDst + i * 32 * VT_STR) =
                *(const s16x8*)(vSrc + (size_t)i * 32 * HWSZ);
    }
    __syncthreads();

    int c = 0;
    for (int it = 0; it < nt; ++it) {
        const bool pre = (it + 1 < nt);
        s16x8 vr[4];
        if (pre) {                       // issue-early V loads for tile it+1
            vSrc += 64;
            #pragma unroll
            for (int i = 0; i < 4; ++i)
                vr[i] = *(const s16x8*)(vSrc + (size_t)i * 32 * HWSZ);
        }

        const unsigned short* Vl = &Vlds[c][0];

        #pragma unroll
        for (int jt = 0; jt < 2; ++jt) {
            // ---- K frags direct from global ----
            const unsigned short* kp = kIt + jt * 32 * 128;
            s16x8 kf[8];
            #pragma unroll
            for (int fs = 0; fs < 8; ++fs)
                kf[fs] = *(const s16x8*)(kp + fs * 16);

            // ---- QK subtile: S'[32j][32q], dual-chain ----
            f32x16 sa, sb;
            #pragma unroll
            for (int i = 0; i < 16; ++i) { sa[i] = 0.f; sb[i] = 0.f; }
            __builtin_amdgcn_s_setprio(1);
            #pragma unroll
            for (int fs = 0; fs < 4; ++fs) {
                sa = __builtin_amdgcn_mfma_f32_32x32x16_bf16(kf[fs], qfrag[fs], sa, 0, 0, 0);
                sb = __builtin_amdgcn_mfma_f32_32x32x16_bf16(kf[fs + 4], qfrag[fs + 4], sb, 0, 0, 0);
            }
            __builtin_amdgcn_s_setprio(0);

            // ---- sigmoid via exp2 (K pre-scaled) + cvt_pk pack ----
            unsigned W0[4], W1[4];
            #pragma unroll
            for (int rg = 0; rg < 4; ++rg) {
                float s0 = sa[4 * rg + 0] + sb[4 * rg + 0];
                float s1 = sa[4 * rg + 1] + sb[4 * rg + 1];
                float s2v = sa[4 * rg + 2] + sb[4 * rg + 2];
                float s3 = sa[4 * rg + 3] + sb[4 * rg + 3];
                float p0 = __builtin_amdgcn_rcpf(1.f + __builtin_amdgcn_exp2f(-s0));
                float p1 = __builtin_amdgcn_rcpf(1.f + __builtin_amdgcn_exp2f(-s1));
                float p2 = __builtin_amdgcn_rcpf(1.f + __builtin_amdgcn_exp2f(-s2v));
                float p3 = __builtin_amdgcn_rcpf(1.f + __builtin_amdgcn_exp2f(-s3));
                W0[rg] = cvt_pk_bf16(p0, p1);
                W1[rg] = cvt_pk_bf16(p2, p3);
            }

            // ---- PV: A-frag via lane^32 exchange; ks = 2*jt + s2 ----
            #pragma unroll
            for (int s2 = 0; s2 < 2; ++s2) {
                unsigned o0 = g ? W0[2 * s2 + 1] : W0[2 * s2];
                unsigned o1 = g ? W1[2 * s2 + 1] : W1[2 * s2];
                unsigned t0 = g ? W0[2 * s2]     : W0[2 * s2 + 1];
                unsigned t1 = g ? W1[2 * s2]     : W1[2 * s2 + 1];
                unsigned r0 = __shfl_xor(t0, 32, 64);
                unsigned r1 = __shfl_xor(t1, 32, 64);
                u32x4 pw;
                pw[0] = g ? r0 : o0;
                pw[1] = g ? r1 : o1;
                pw[2] = g ? o0 : r0;
                pw[3] = g ? o1 : r1;
                s16x8 pf = __builtin_bit_cast(s16x8, pw);
                const int ks = 2 * jt + s2;
                __builtin_amdgcn_s_setprio(1);
                #pragma unroll
                for (int ft = 0; ft < 4; ++ft) {
                    s16x8 vf = *(const s16x8*)(Vl + (size_t)(32 * ft + l31) * VT_STR + ks * 16 + g * 8);
                    acc[ft] = __builtin_amdgcn_mfma_f32_32x32x16_bf16(pf, vf, acc[ft], 0, 0, 0);
                }
                __builtin_amdgcn_s_setprio(0);
            }
        }
        kIt += 64 * 128;

        if (pre) {                       // write-late into other buffer
            #pragma unroll
            for (int i = 0; i < 4; ++i)
                *(s16x8*)(&Vlds[c ^ 1][0] + vDst + i * 32 * VT_STR) = vr[i];
        }
        __syncthreads();
        c ^= 1;
    }

    // ---- epilogue: direct store of wave-private 32q x 128f partial ----
    float* op = outp + (size_t)split * ((size_t)NBATCH * HWSZ * 128);
    #pragma unroll
    for (int ft = 0; ft < 4; ++ft)
    #pragma unroll
    for (int r2 = 0; r2 < 16; ++r2) {
        int row = (r2 & 3) + 8 * (r2 >> 2) + 4 * g;
        int q = qb + 32 * qt + row;
        size_t o = (((size_t)(b * HWSZ + q)) << 7) + 32 * ft + l31;
        op[o] = acc[ft][r2];
    }
}

// ---------------- Kernel 2b: QBLK=64 fallback (2-split / no-split) ----------------
template<bool SPLIT>
__global__ __launch_bounds__(256, 2) void attn_kernel(
    const unsigned short* __restrict__ Kbf,
    const unsigned short* __restrict__ Qbf,
    const unsigned short* __restrict__ Vtbf,
    const float* __restrict__ resid,
    float* __restrict__ outp)
{
    __shared__ __align__(16) char smem[2 * BUF_BYTES];

    const int t    = threadIdx.x;
    const int lane = t & 63;
    const int w    = t >> 6;
    const int qt   = w & 1;
    const int jt   = w >> 1;
    const int l31  = lane & 31;
    const int g    = lane >> 5;

    int bid = blockIdx.x;
    int half = 0;
    if (SPLIT) { half = bid >> 8; bid &= 255; }
    const int b      = bid >> 6;
    const int qb     = (bid & 63) * 64;
    const int jBegin = half * (HWSZ / 2);
    const int nt     = (SPLIT ? HWSZ / 2 : HWSZ) / 64;

    s16x8 qfrag[8];
    {
        const unsigned short* qp =
            Qbf + (((size_t)(b * HWSZ + qb + 32 * qt + l31)) << 7) + g * 8;
        #pragma unroll
        for (int fs = 0; fs < 8; ++fs)
            qfrag[fs] = *(const s16x8*)(qp + fs * 16);
    }

    f32x16 acc[4];
    #pragma unroll
    for (int ft = 0; ft < 4; ++ft)
        #pragma unroll
        for (int i = 0; i < 16; ++i) acc[ft][i] = 0.f;

    const unsigned short* Kbase = Kbf  + (((size_t)b * HWSZ) << 7);
    const unsigned short* Vbase = Vtbf + (((size_t)b) << 7) * HWSZ;

    const unsigned short* kSrc = Kbase + (size_t)(jBegin + (t >> 4)) * 128 + (t & 15) * 8;
    const unsigned short* vSrc = Vbase + (size_t)(t >> 3) * HWSZ + jBegin + (t & 7) * 8;
    const int kDst = (t >> 4) * KT_STR + (t & 15) * 8;
    const int vDst = (t >> 3) * VT_STR + (t & 7) * 8;

    {
        unsigned short* Kl = (unsigned short*)smem;
        unsigned short* Vl = (unsigned short*)(smem + KT_BYTES);
        #pragma unroll
        for (int i = 0; i < 4; ++i)
            *(s16x8*)(Kl + kDst + i * 16 * KT_STR) = *(const s16x8*)(kSrc + (size_t)i * 2048);
        #pragma unroll
        for (int i = 0; i < 4; ++i)
            *(s16x8*)(Vl + vDst + i * 32 * VT_STR) = *(const s16x8*)(vSrc + (size_t)i * 32 * HWSZ);
    }
    __syncthreads();

    int c = 0;
    for (int it = 0; it < nt; ++it) {
        const bool pre = (it + 1 < nt);
        s16x8 kr[4], vr[4];
        if (pre) {
            kSrc += 64 * 128;
            vSrc += 64;
            #pragma unroll
            for (int i = 0; i < 4; ++i)
                kr[i] = *(const s16x8*)(kSrc + (size_t)i * 2048);
            #pragma unroll
            for (int i = 0; i < 4; ++i)
                vr[i] = *(const s16x8*)(vSrc + (size_t)i * 32 * HWSZ);
        }

        const unsigned short* Kl = (const unsigned short*)(smem + c * BUF_BYTES);
        const unsigned short* Vl = (const unsigned short*)(smem + c * BUF_BYTES + KT_BYTES);

        f32x16 sa, sb;
        #pragma unroll
        for (int i = 0; i < 16; ++i) { sa[i] = 0.f; sb[i] = 0.f; }
        const unsigned short* Krow = Kl + (size_t)(32 * jt + l31) * KT_STR + g * 8;
        __builtin_amdgcn_s_setprio(1);
        #pragma unroll
        for (int fs = 0; fs < 4; ++fs) {
            sa = __builtin_amdgcn_mfma_f32_32x32x16_bf16(
                     *(const s16x8*)(Krow + fs * 16), qfrag[fs], sa, 0, 0, 0);
            sb = __builtin_amdgcn_mfma_f32_32x32x16_bf16(
                     *(const s16x8*)(Krow + (fs + 4) * 16), qfrag[fs + 4], sb, 0, 0, 0);
        }
        __builtin_amdgcn_s_setprio(0);

        unsigned W0[4], W1[4];
        #pragma unroll
        for (int rg = 0; rg < 4; ++rg) {
            float s0 = sa[4 * rg + 0] + sb[4 * rg + 0];
            float s1 = sa[4 * rg + 1] + sb[4 * rg + 1];
            float s2v = sa[4 * rg + 2] + sb[4 * rg + 2];
            float s3 = sa[4 * rg + 3] + sb[4 * rg + 3];
            float p0 = __builtin_amdgcn_rcpf(1.f + __builtin_amdgcn_exp2f(-s0));
            float p1 = __builtin_amdgcn_rcpf(1.f + __builtin_amdgcn_exp2f(-s1));
            float p2 = __builtin_amdgcn_rcpf(1.f + __builtin_amdgcn_exp2f(-s2v));
            float p3 = __builtin_amdgcn_rcpf(1.f + __builtin_amdgcn_exp2f(-s3));
            W0[rg] = cvt_pk_bf16(p0, p1);
            W1[rg] = cvt_pk_bf16(p2, p3);
        }

        #pragma unroll
        for (int s2 = 0; s2 < 2; ++s2) {
            unsigned o0 = g ? W0[2 * s2 + 1] : W0[2 * s2];
            unsigned o1 = g ? W1[2 * s2 + 1] : W1[2 * s2];
            unsigned t0 = g ? W0[2 * s2]     : W0[2 * s2 + 1];
            unsigned t1 = g ? W1[2 * s2]     : W1[2 * s2 + 1];
            unsigned r0 = __shfl_xor(t0, 32, 64);
            unsigned r1 = __shfl_xor(t1, 32, 64);
            u32x4 pw;
            pw[0] = g ? r0 : o0;
            pw[1] = g ? r1 : o1;
            pw[2] = g ? o0 : r0;
            pw[3] = g ? o1 : r1;
            s16x8 pf = __builtin_bit_cast(s16x8, pw);
            const int ks = 2 * jt + s2;
            __builtin_amdgcn_s_setprio(1);
            #pragma unroll
            for (int ft = 0; ft < 4; ++ft) {
                s16x8 vf = *(const s16x8*)(Vl + (size_t)(32 * ft + l31) * VT_STR + ks * 16 + g * 8);
                acc[ft] = __builtin_amdgcn_mfma_f32_32x32x16_bf16(pf, vf, acc[ft], 0, 0, 0);
            }
            __builtin_amdgcn_s_setprio(0);
        }

        if (pre) {
            unsigned short* Kd = (unsigned short*)(smem + (c ^ 1) * BUF_BYTES);
            unsigned short* Vd = (unsigned short*)(smem + (c ^ 1) * BUF_BYTES + KT_BYTES);
            #pragma unroll
            for (int i = 0; i < 4; ++i)
                *(s16x8*)(Kd + kDst + i * 16 * KT_STR) = kr[i];
            #pragma unroll
            for (int i = 0; i < 4; ++i)
                *(s16x8*)(Vd + vDst + i * 32 * VT_STR) = vr[i];
        }
        __syncthreads();
        c ^= 1;
    }

    float* red = (float*)smem;
    if (jt == 1) {
        #pragma unroll
        for (int ft = 0; ft < 4; ++ft)
        #pragma unroll
        for (int r = 0; r < 16; ++r) {
            int row = (r & 3) + 8 * (r >> 2) + 4 * g;
            red[qt * 4096 + row * 128 + 32 * ft + l31] = acc[ft][r];
        }
    }
    __syncthreads();
    if (jt == 0) {
        float* op = outp + (SPLIT ? (size_t)half * ((size_t)NBATCH * HWSZ * 128) : 0);
        #pragma unroll
        for (int ft = 0; ft < 4; ++ft)
        #pragma unroll
        for (int r = 0; r < 16; ++r) {
            int row = (r & 3) + 8 * (r >> 2) + 4 * g;
            float v = acc[ft][r] + red[qt * 4096 + row * 128 + 32 * ft + l31];
            int q = qb + 32 * qt + row;
            size_t o = (((size_t)(b * HWSZ + q)) << 7) + 32 * ft + l31;
            if (SPLIT) op[o] = v;
            else       op[o] = v + resid[o];
        }
    }
}

// ---------------- Kernel 3: partial reduce + residual ----------------
__global__ __launch_bounds__(256, 1) void reduce2_kernel(
    const float* __restrict__ p0, const float* __restrict__ p1, float* outp)
{
    int i = blockIdx.x * 256 + threadIdx.x;
    f32x4 a = ((const f32x4*)p0)[i];
    f32x4 b = ((const f32x4*)p1)[i];
    f32x4 c = ((f32x4*)outp)[i];
    ((f32x4*)outp)[i] = a + b + c;
}

template<int S>
__global__ __launch_bounds__(256, 1) void reduceN_kernel(
    const float* __restrict__ parts, float* __restrict__ outp)
{
    const size_t N4 = (size_t)NBATCH * HWSZ * 128 / 4;
    size_t i = (size_t)blockIdx.x * 256 + threadIdx.x;
    f32x4 s = ((f32x4*)outp)[i];          // xq residual
    #pragma unroll
    for (int k = 0; k < S; ++k)
        s += ((const f32x4*)parts)[i + (size_t)k * N4];
    ((f32x4*)outp)[i] = s;
}

extern "C" void kernel_launch(void* const* d_in, const int* in_sizes, int n_in,
                              void* d_out, int out_size, void* d_ws, size_t ws_size,
                              hipStream_t stream) {
    const float* x  = (const float*)d_in[0];
    const float* y  = (const float*)d_in[1];
    const float* W1 = (const float*)d_in[2];
    const float* b1 = (const float*)d_in[3];
    const float* W2 = (const float*)d_in[4];
    const float* b2 = (const float*)d_in[5];
    float* out = (float*)d_out;

    const size_t NELEM = (size_t)NBATCH * HWSZ * 128;   // 2,097,152
    unsigned short* xq_bf  = (unsigned short*)d_ws;
    unsigned short* yk_bf  = xq_bf + NELEM;
    unsigned short* ykT_bf = yk_bf + NELEM;
    float* part = (float*)(ykT_bf + NELEM);

    proj_kernel<<<(int)(NBATCH * HWSZ / 64), 256, 0, stream>>>(
        x, y, W1, b1, W2, b2, out, xq_bf, yk_bf, ykT_bf);

    if (ws_size >= NELEM * (6 + 32)) {               // 79.7 MB: QBLK=128, 8-split
        attn128v2_kernel<8><<<1024, 256, 0, stream>>>(xq_bf, yk_bf, ykT_bf, part);
        reduceN_kernel<8><<<(int)(NELEM / 1024), 256, 0, stream>>>(part, out);
    } else if (ws_size >= NELEM * (6 + 16)) {        // 46.1 MB: QBLK=128, 4-split
        attn128v2_kernel<4><<<512, 256, 0, stream>>>(xq_bf, yk_bf, ykT_bf, part);
        reduceN_kernel<4><<<(int)(NELEM / 1024), 256, 0, stream>>>(part, out);
    } else if (ws_size >= NELEM * (6 + 8)) {         // 29.4 MB: QBLK=64, 2-split
        attn_kernel<true><<<512, 256, 0, stream>>>(xq_bf, yk_bf, ykT_bf, out, part);
        reduce2_kernel<<<(int)(NELEM / 1024), 256, 0, stream>>>(part, part + NELEM, out);
    } else {
        attn_kernel<false><<<256, 256, 0, stream>>>(xq_bf, yk_bf, ykT_bf, out, out);
    }
}

// Round 8
// 69.527 us; speedup vs baseline: 3.3026x; 1.5121x over previous
//
#include <hip/hip_runtime.h>
#include <hip/hip_bf16.h>
#include <stdint.h>

typedef float f32x16 __attribute__((ext_vector_type(16)));
typedef float f32x4  __attribute__((ext_vector_type(4)));
typedef short s16x8  __attribute__((ext_vector_type(8)));
typedef unsigned int u32x4 __attribute__((ext_vector_type(4)));

#define HWSZ   4096
#define NBATCH 4
#define LOG2E  1.44269504088896340736f

__device__ __forceinline__ unsigned short f2bf(float f) {
    unsigned u = __builtin_bit_cast(unsigned, f);
    u += 0x7FFFu + ((u >> 16) & 1u);          // RTNE
    return (unsigned short)(u >> 16);
}
__device__ __forceinline__ unsigned cvt_pk_bf16(float lo, float hi) {
    __hip_bfloat162 h = __float22bfloat162_rn(make_float2(lo, hi));
    return *reinterpret_cast<unsigned*>(&h);   // v_cvt_pk_bf16_f32
}

// ---------------- Kernel 1: MFMA projections ----------------
// xq = x@W1 + b1 -> d_out (f32 residual) + xq_bf (bf16, PRE-SCALED by log2e: K-only)
// yk = y@W2 + b2 -> yk_bf (bf16) + ykT_bf (bf16 transposed)
__global__ __launch_bounds__(256, 1) void proj_kernel(
    const float* __restrict__ x, const float* __restrict__ y,
    const float* __restrict__ W1, const float* __restrict__ b1,
    const float* __restrict__ W2, const float* __restrict__ b2,
    float* __restrict__ xq_f32,
    unsigned short* __restrict__ xq_bf,
    unsigned short* __restrict__ yk_bf,
    unsigned short* __restrict__ ykT_bf)
{
    __shared__ unsigned short Xlds[64][136];
    __shared__ unsigned short Ylds[64][136];
    __shared__ unsigned short Tlds[128][72];

    const int t    = threadIdx.x;
    const int lane = t & 63;
    const int w    = t >> 6;
    const int l31  = lane & 31;
    const int g    = lane >> 5;
    const int r0   = blockIdx.x * 64;
    const int b    = r0 >> 12;
    const int j0   = r0 & (HWSZ - 1);

    #pragma unroll
    for (int i = 0; i < 8; ++i) {
        int li = t + 256 * i;
        int row = li >> 5, c = (li & 31) * 4;
        float4 vx = *(const float4*)(x + (size_t)(r0 + row) * 128 + c);
        float4 vy = *(const float4*)(y + (size_t)(r0 + row) * 128 + c);
        *(uint2*)&Xlds[row][c] = make_uint2(cvt_pk_bf16(vx.x, vx.y), cvt_pk_bf16(vx.z, vx.w));
        *(uint2*)&Ylds[row][c] = make_uint2(cvt_pk_bf16(vy.x, vy.y), cvt_pk_bf16(vy.z, vy.w));
    }
    __syncthreads();

    const int m  = w >> 1;
    const int fh = w & 1;
    const float* Wm = m ? W2 : W1;
    const float* bm = m ? b2 : b1;
    const unsigned short* A0 = m ? &Ylds[0][0] : &Xlds[0][0];

    f32x16 acc[2][2];
    #pragma unroll
    for (int i = 0; i < 16; ++i) {
        acc[0][0][i] = 0.f; acc[0][1][i] = 0.f;
        acc[1][0][i] = 0.f; acc[1][1][i] = 0.f;
    }

    #pragma unroll
    for (int ks = 0; ks < 8; ++ks) {
        s16x8 bfr[2];
        #pragma unroll
        for (int ft = 0; ft < 2; ++ft) {
            const float* wp = Wm + (size_t)(ks * 16 + g * 8) * 128 + fh * 64 + ft * 32 + l31;
            #pragma unroll
            for (int i = 0; i < 8; ++i)
                bfr[ft][i] = (short)f2bf(wp[(size_t)i * 128]);
        }
        #pragma unroll
        for (int rt = 0; rt < 2; ++rt) {
            s16x8 af = *(const s16x8*)(A0 + (size_t)(rt * 32 + l31) * 136 + ks * 16 + g * 8);
            acc[rt][0] = __builtin_amdgcn_mfma_f32_32x32x16_bf16(af, bfr[0], acc[rt][0], 0, 0, 0);
            acc[rt][1] = __builtin_amdgcn_mfma_f32_32x32x16_bf16(af, bfr[1], acc[rt][1], 0, 0, 0);
        }
    }

    const float bias_v[2] = { bm[fh * 64 + l31], bm[fh * 64 + 32 + l31] };

    if (m == 0) {
        #pragma unroll
        for (int rt = 0; rt < 2; ++rt)
        #pragma unroll
        for (int ft = 0; ft < 2; ++ft) {
            int f = fh * 64 + ft * 32 + l31;
            #pragma unroll
            for (int r = 0; r < 16; ++r) {
                int row = rt * 32 + (r & 3) + 8 * (r >> 2) + 4 * g;
                float v = acc[rt][ft][r] + bias_v[ft];
                size_t o = (size_t)(r0 + row) * 128 + f;
                xq_f32[o] = v;
                xq_bf[o]  = f2bf(v * LOG2E);      // K pre-scaled for exp2 sigmoid
            }
        }
    } else {
        #pragma unroll
        for (int rt = 0; rt < 2; ++rt)
        #pragma unroll
        for (int ft = 0; ft < 2; ++ft) {
            int f = fh * 64 + ft * 32 + l31;
            #pragma unroll
            for (int rg = 0; rg < 4; ++rg) {
                float p0 = acc[rt][ft][4 * rg + 0] + bias_v[ft];
                float p1 = acc[rt][ft][4 * rg + 1] + bias_v[ft];
                float p2 = acc[rt][ft][4 * rg + 2] + bias_v[ft];
                float p3 = acc[rt][ft][4 * rg + 3] + bias_v[ft];
                int jb = rt * 32 + 8 * rg + 4 * g;
                *(uint2*)&Tlds[f][jb] = make_uint2(cvt_pk_bf16(p0, p1), cvt_pk_bf16(p2, p3));
                size_t o = (size_t)(r0 + jb) * 128 + f;
                yk_bf[o]       = f2bf(p0);
                yk_bf[o + 128] = f2bf(p1);
                yk_bf[o + 256] = f2bf(p2);
                yk_bf[o + 384] = f2bf(p3);
            }
        }
    }
    __syncthreads();

    {
        int f  = t >> 1;
        int jh = (t & 1) * 32;
        unsigned short* dst = ykT_bf + ((size_t)(b * 128 + f)) * HWSZ + j0 + jh;
        #pragma unroll
        for (int c = 0; c < 4; ++c)
            *(s16x8*)(dst + c * 8) = *(const s16x8*)&Tlds[f][jh + c * 8];
    }
}

// ---------------- shared attention LDS geometry ----------------
#define KT_STR   136
#define VT_STR   72
#define KT_BYTES (64 * KT_STR * 2)     // 17408
#define VT_BYTES (128 * VT_STR * 2)    // 18432
#define BUF_BYTES (KT_BYTES + VT_BYTES)

// ---------------- Kernel 2a: QBLK=128 attention (R5 structure + permlane) ----
// 4 waves = q-tiles 0..3. Per staged 64-j tile: 2 j-subtiles of {8 QK MFMA,
// sigmoid, permlane32_swap exchange, 8 PV MFMA} => 32 MFMA/wave/barrier.
// K+V double-buffered in LDS; reg-staged issue-early/write-late.
__global__ __launch_bounds__(256, 2) void attn128_kernel(
    const unsigned short* __restrict__ Kbf,   // xq_bf (log2e-scaled) [b][j][128]
    const unsigned short* __restrict__ Qbf,   // yk_bf  [b][q][128]
    const unsigned short* __restrict__ Vtbf,  // ykT_bf [b][128][4096]
    float* __restrict__ outp)                 // partials base (4 x NELEM)
{
    __shared__ __align__(16) char smem[2 * BUF_BYTES];

    const int t    = threadIdx.x;
    const int lane = t & 63;
    const int qt   = t >> 6;
    const int l31  = lane & 31;
    const int g    = lane >> 5;

    const int split  = blockIdx.x >> 7;       // 0..3
    const int r      = blockIdx.x & 127;
    const int b      = r >> 5;
    const int qb     = (r & 31) * 128;
    const int jBegin = split * (HWSZ / 4);
    const int nt     = (HWSZ / 4) / 64;       // 16

    s16x8 qfrag[8];
    {
        const unsigned short* qp =
            Qbf + (((size_t)(b * HWSZ + qb + 32 * qt + l31)) << 7) + g * 8;
        #pragma unroll
        for (int fs = 0; fs < 8; ++fs)
            qfrag[fs] = *(const s16x8*)(qp + fs * 16);
    }

    f32x16 acc[4];
    #pragma unroll
    for (int ft = 0; ft < 4; ++ft)
        #pragma unroll
        for (int i = 0; i < 16; ++i) acc[ft][i] = 0.f;

    const unsigned short* Kbase = Kbf  + (((size_t)b * HWSZ) << 7);
    const unsigned short* Vbase = Vtbf + (((size_t)b) << 7) * HWSZ;

    const unsigned short* kSrc = Kbase + (size_t)(jBegin + (t >> 4)) * 128 + (t & 15) * 8;
    const unsigned short* vSrc = Vbase + (size_t)(t >> 3) * HWSZ + jBegin + (t & 7) * 8;
    const int kDst = (t >> 4) * KT_STR + (t & 15) * 8;
    const int vDst = (t >> 3) * VT_STR + (t & 7) * 8;

    {   // prologue: stage tile 0 into buf 0
        unsigned short* Kl = (unsigned short*)smem;
        unsigned short* Vl = (unsigned short*)(smem + KT_BYTES);
        #pragma unroll
        for (int i = 0; i < 4; ++i)
            *(s16x8*)(Kl + kDst + i * 16 * KT_STR) = *(const s16x8*)(kSrc + (size_t)i * 2048);
        #pragma unroll
        for (int i = 0; i < 4; ++i)
            *(s16x8*)(Vl + vDst + i * 32 * VT_STR) = *(const s16x8*)(vSrc + (size_t)i * 32 * HWSZ);
    }
    __syncthreads();

    int c = 0;
    for (int it = 0; it < nt; ++it) {
        const bool pre = (it + 1 < nt);
        s16x8 kr[4], vr[4];
        if (pre) {                       // issue-early loads for tile it+1
            kSrc += 64 * 128;
            vSrc += 64;
            #pragma unroll
            for (int i = 0; i < 4; ++i)
                kr[i] = *(const s16x8*)(kSrc + (size_t)i * 2048);
            #pragma unroll
            for (int i = 0; i < 4; ++i)
                vr[i] = *(const s16x8*)(vSrc + (size_t)i * 32 * HWSZ);
        }

        const unsigned short* Kl = (const unsigned short*)(smem + c * BUF_BYTES);
        const unsigned short* Vl = (const unsigned short*)(smem + c * BUF_BYTES + KT_BYTES);

        #pragma unroll
        for (int jt = 0; jt < 2; ++jt) {
            // ---- QK subtile: S'[32j][32q], dual-chain ----
            f32x16 sa, sb;
            #pragma unroll
            for (int i = 0; i < 16; ++i) { sa[i] = 0.f; sb[i] = 0.f; }
            const unsigned short* Krow = Kl + (size_t)(32 * jt + l31) * KT_STR + g * 8;
            __builtin_amdgcn_s_setprio(1);
            #pragma unroll
            for (int fs = 0; fs < 4; ++fs) {
                sa = __builtin_amdgcn_mfma_f32_32x32x16_bf16(
                         *(const s16x8*)(Krow + fs * 16), qfrag[fs], sa, 0, 0, 0);
                sb = __builtin_amdgcn_mfma_f32_32x32x16_bf16(
                         *(const s16x8*)(Krow + (fs + 4) * 16), qfrag[fs + 4], sb, 0, 0, 0);
            }
            __builtin_amdgcn_s_setprio(0);

            // ---- sigmoid via exp2 (K pre-scaled) + cvt_pk pack ----
            unsigned W0[4], W1[4];
            #pragma unroll
            for (int rg = 0; rg < 4; ++rg) {
                float s0 = sa[4 * rg + 0] + sb[4 * rg + 0];
                float s1 = sa[4 * rg + 1] + sb[4 * rg + 1];
                float s2v = sa[4 * rg + 2] + sb[4 * rg + 2];
                float s3 = sa[4 * rg + 3] + sb[4 * rg + 3];
                float p0 = __builtin_amdgcn_rcpf(1.f + __builtin_amdgcn_exp2f(-s0));
                float p1 = __builtin_amdgcn_rcpf(1.f + __builtin_amdgcn_exp2f(-s1));
                float p2 = __builtin_amdgcn_rcpf(1.f + __builtin_amdgcn_exp2f(-s2v));
                float p3 = __builtin_amdgcn_rcpf(1.f + __builtin_amdgcn_exp2f(-s3));
                W0[rg] = cvt_pk_bf16(p0, p1);
                W1[rg] = cvt_pk_bf16(p2, p3);
            }

            // ---- PV: A-frags via v_permlane32_swap_b32 (pure VALU, no DS) ----
            // With A=W0[2s2], B=W0[2s2+1]: swap A.hi<->B.lo gives
            // A'={A.lo,B.lo}=pw[0], B'={A.hi,B.hi}=pw[2]  (same for W1 pair).
            #pragma unroll
            for (int s2 = 0; s2 < 2; ++s2) {
                unsigned a0 = W0[2 * s2], b0 = W0[2 * s2 + 1];
                unsigned a1 = W1[2 * s2], b1 = W1[2 * s2 + 1];
                asm("v_permlane32_swap_b32 %0, %1" : "+v"(a0), "+v"(b0));
                asm("v_permlane32_swap_b32 %0, %1" : "+v"(a1), "+v"(b1));
                u32x4 pw;
                pw[0] = a0; pw[1] = a1; pw[2] = b0; pw[3] = b1;
                s16x8 pf = __builtin_bit_cast(s16x8, pw);
                const int ks = 2 * jt + s2;
                __builtin_amdgcn_s_setprio(1);
                #pragma unroll
                for (int ft = 0; ft < 4; ++ft) {
                    s16x8 vf = *(const s16x8*)(Vl + (size_t)(32 * ft + l31) * VT_STR + ks * 16 + g * 8);
                    acc[ft] = __builtin_amdgcn_mfma_f32_32x32x16_bf16(pf, vf, acc[ft], 0, 0, 0);
                }
                __builtin_amdgcn_s_setprio(0);
            }
        }

        if (pre) {                       // write-late into other buffer
            unsigned short* Kd = (unsigned short*)(smem + (c ^ 1) * BUF_BYTES);
            unsigned short* Vd = (unsigned short*)(smem + (c ^ 1) * BUF_BYTES + KT_BYTES);
            #pragma unroll
            for (int i = 0; i < 4; ++i)
                *(s16x8*)(Kd + kDst + i * 16 * KT_STR) = kr[i];
            #pragma unroll
            for (int i = 0; i < 4; ++i)
                *(s16x8*)(Vd + vDst + i * 32 * VT_STR) = vr[i];
        }
        __syncthreads();
        c ^= 1;
    }

    // ---- epilogue: direct store of wave-private 32q x 128f partial ----
    float* op = outp + (size_t)split * ((size_t)NBATCH * HWSZ * 128);
    #pragma unroll
    for (int ft = 0; ft < 4; ++ft)
    #pragma unroll
    for (int r2 = 0; r2 < 16; ++r2) {
        int row = (r2 & 3) + 8 * (r2 >> 2) + 4 * g;
        int q = qb + 32 * qt + row;
        size_t o = (((size_t)(b * HWSZ + q)) << 7) + 32 * ft + l31;
        op[o] = acc[ft][r2];
    }
}

// ---------------- Kernel 2b: QBLK=64 fallback (2-split / no-split) ----------------
template<bool SPLIT>
__global__ __launch_bounds__(256, 2) void attn_kernel(
    const unsigned short* __restrict__ Kbf,
    const unsigned short* __restrict__ Qbf,
    const unsigned short* __restrict__ Vtbf,
    const float* __restrict__ resid,
    float* __restrict__ outp)
{
    __shared__ __align__(16) char smem[2 * BUF_BYTES];

    const int t    = threadIdx.x;
    const int lane = t & 63;
    const int w    = t >> 6;
    const int qt   = w & 1;
    const int jt   = w >> 1;
    const int l31  = lane & 31;
    const int g    = lane >> 5;

    int bid = blockIdx.x;
    int half = 0;
    if (SPLIT) { half = bid >> 8; bid &= 255; }
    const int b      = bid >> 6;
    const int qb     = (bid & 63) * 64;
    const int jBegin = half * (HWSZ / 2);
    const int nt     = (SPLIT ? HWSZ / 2 : HWSZ) / 64;

    s16x8 qfrag[8];
    {
        const unsigned short* qp =
            Qbf + (((size_t)(b * HWSZ + qb + 32 * qt + l31)) << 7) + g * 8;
        #pragma unroll
        for (int fs = 0; fs < 8; ++fs)
            qfrag[fs] = *(const s16x8*)(qp + fs * 16);
    }

    f32x16 acc[4];
    #pragma unroll
    for (int ft = 0; ft < 4; ++ft)
        #pragma unroll
        for (int i = 0; i < 16; ++i) acc[ft][i] = 0.f;

    const unsigned short* Kbase = Kbf  + (((size_t)b * HWSZ) << 7);
    const unsigned short* Vbase = Vtbf + (((size_t)b) << 7) * HWSZ;

    const unsigned short* kSrc = Kbase + (size_t)(jBegin + (t >> 4)) * 128 + (t & 15) * 8;
    const unsigned short* vSrc = Vbase + (size_t)(t >> 3) * HWSZ + jBegin + (t & 7) * 8;
    const int kDst = (t >> 4) * KT_STR + (t & 15) * 8;
    const int vDst = (t >> 3) * VT_STR + (t & 7) * 8;

    {
        unsigned short* Kl = (unsigned short*)smem;
        unsigned short* Vl = (unsigned short*)(smem + KT_BYTES);
        #pragma unroll
        for (int i = 0; i < 4; ++i)
            *(s16x8*)(Kl + kDst + i * 16 * KT_STR) = *(const s16x8*)(kSrc + (size_t)i * 2048);
        #pragma unroll
        for (int i = 0; i < 4; ++i)
            *(s16x8*)(Vl + vDst + i * 32 * VT_STR) = *(const s16x8*)(vSrc + (size_t)i * 32 * HWSZ);
    }
    __syncthreads();

    int c = 0;
    for (int it = 0; it < nt; ++it) {
        const bool pre = (it + 1 < nt);
        s16x8 kr[4], vr[4];
        if (pre) {
            kSrc += 64 * 128;
            vSrc += 64;
            #pragma unroll
            for (int i = 0; i < 4; ++i)
                kr[i] = *(const s16x8*)(kSrc + (size_t)i * 2048);
            #pragma unroll
            for (int i = 0; i < 4; ++i)
                vr[i] = *(const s16x8*)(vSrc + (size_t)i * 32 * HWSZ);
        }

        const unsigned short* Kl = (const unsigned short*)(smem + c * BUF_BYTES);
        const unsigned short* Vl = (const unsigned short*)(smem + c * BUF_BYTES + KT_BYTES);

        f32x16 sa, sb;
        #pragma unroll
        for (int i = 0; i < 16; ++i) { sa[i] = 0.f; sb[i] = 0.f; }
        const unsigned short* Krow = Kl + (size_t)(32 * jt + l31) * KT_STR + g * 8;
        __builtin_amdgcn_s_setprio(1);
        #pragma unroll
        for (int fs = 0; fs < 4; ++fs) {
            sa = __builtin_amdgcn_mfma_f32_32x32x16_bf16(
                     *(const s16x8*)(Krow + fs * 16), qfrag[fs], sa, 0, 0, 0);
            sb = __builtin_amdgcn_mfma_f32_32x32x16_bf16(
                     *(const s16x8*)(Krow + (fs + 4) * 16), qfrag[fs + 4], sb, 0, 0, 0);
        }
        __builtin_amdgcn_s_setprio(0);

        unsigned W0[4], W1[4];
        #pragma unroll
        for (int rg = 0; rg < 4; ++rg) {
            float s0 = sa[4 * rg + 0] + sb[4 * rg + 0];
            float s1 = sa[4 * rg + 1] + sb[4 * rg + 1];
            float s2v = sa[4 * rg + 2] + sb[4 * rg + 2];
            float s3 = sa[4 * rg + 3] + sb[4 * rg + 3];
            float p0 = __builtin_amdgcn_rcpf(1.f + __builtin_amdgcn_exp2f(-s0));
            float p1 = __builtin_amdgcn_rcpf(1.f + __builtin_amdgcn_exp2f(-s1));
            float p2 = __builtin_amdgcn_rcpf(1.f + __builtin_amdgcn_exp2f(-s2v));
            float p3 = __builtin_amdgcn_rcpf(1.f + __builtin_amdgcn_exp2f(-s3));
            W0[rg] = cvt_pk_bf16(p0, p1);
            W1[rg] = cvt_pk_bf16(p2, p3);
        }

        #pragma unroll
        for (int s2 = 0; s2 < 2; ++s2) {
            unsigned a0 = W0[2 * s2], b0 = W0[2 * s2 + 1];
            unsigned a1 = W1[2 * s2], b1 = W1[2 * s2 + 1];
            asm("v_permlane32_swap_b32 %0, %1" : "+v"(a0), "+v"(b0));
            asm("v_permlane32_swap_b32 %0, %1" : "+v"(a1), "+v"(b1));
            u32x4 pw;
            pw[0] = a0; pw[1] = a1; pw[2] = b0; pw[3] = b1;
            s16x8 pf = __builtin_bit_cast(s16x8, pw);
            const int ks = 2 * jt + s2;
            __builtin_amdgcn_s_setprio(1);
            #pragma unroll
            for (int ft = 0; ft < 4; ++ft) {
                s16x8 vf = *(const s16x8*)(Vl + (size_t)(32 * ft + l31) * VT_STR + ks * 16 + g * 8);
                acc[ft] = __builtin_amdgcn_mfma_f32_32x32x16_bf16(pf, vf, acc[ft], 0, 0, 0);
            }
            __builtin_amdgcn_s_setprio(0);
        }

        if (pre) {
            unsigned short* Kd = (unsigned short*)(smem + (c ^ 1) * BUF_BYTES);
            unsigned short* Vd = (unsigned short*)(smem + (c ^ 1) * BUF_BYTES + KT_BYTES);
            #pragma unroll
            for (int i = 0; i < 4; ++i)
                *(s16x8*)(Kd + kDst + i * 16 * KT_STR) = kr[i];
            #pragma unroll
            for (int i = 0; i < 4; ++i)
                *(s16x8*)(Vd + vDst + i * 32 * VT_STR) = vr[i];
        }
        __syncthreads();
        c ^= 1;
    }

    float* red = (float*)smem;
    if (jt == 1) {
        #pragma unroll
        for (int ft = 0; ft < 4; ++ft)
        #pragma unroll
        for (int r = 0; r < 16; ++r) {
            int row = (r & 3) + 8 * (r >> 2) + 4 * g;
            red[qt * 4096 + row * 128 + 32 * ft + l31] = acc[ft][r];
        }
    }
    __syncthreads();
    if (jt == 0) {
        float* op = outp + (SPLIT ? (size_t)half * ((size_t)NBATCH * HWSZ * 128) : 0);
        #pragma unroll
        for (int ft = 0; ft < 4; ++ft)
        #pragma unroll
        for (int r = 0; r < 16; ++r) {
            int row = (r & 3) + 8 * (r >> 2) + 4 * g;
            float v = acc[ft][r] + red[qt * 4096 + row * 128 + 32 * ft + l31];
            int q = qb + 32 * qt + row;
            size_t o = (((size_t)(b * HWSZ + q)) << 7) + 32 * ft + l31;
            if (SPLIT) op[o] = v;
            else       op[o] = v + resid[o];
        }
    }
}

// ---------------- Kernel 3: partial reduce + residual ----------------
__global__ __launch_bounds__(256, 1) void reduce2_kernel(
    const float* __restrict__ p0, const float* __restrict__ p1, float* outp)
{
    int i = blockIdx.x * 256 + threadIdx.x;
    f32x4 a = ((const f32x4*)p0)[i];
    f32x4 b = ((const f32x4*)p1)[i];
    f32x4 c = ((f32x4*)outp)[i];
    ((f32x4*)outp)[i] = a + b + c;
}

template<int S>
__global__ __launch_bounds__(256, 1) void reduceN_kernel(
    const float* __restrict__ parts, float* __restrict__ outp)
{
    const size_t N4 = (size_t)NBATCH * HWSZ * 128 / 4;
    size_t i = (size_t)blockIdx.x * 256 + threadIdx.x;
    f32x4 s = ((f32x4*)outp)[i];          // xq residual
    #pragma unroll
    for (int k = 0; k < S; ++k)
        s += ((const f32x4*)parts)[i + (size_t)k * N4];
    ((f32x4*)outp)[i] = s;
}

extern "C" void kernel_launch(void* const* d_in, const int* in_sizes, int n_in,
                              void* d_out, int out_size, void* d_ws, size_t ws_size,
                              hipStream_t stream) {
    const float* x  = (const float*)d_in[0];
    const float* y  = (const float*)d_in[1];
    const float* W1 = (const float*)d_in[2];
    const float* b1 = (const float*)d_in[3];
    const float* W2 = (const float*)d_in[4];
    const float* b2 = (const float*)d_in[5];
    float* out = (float*)d_out;

    const size_t NELEM = (size_t)NBATCH * HWSZ * 128;   // 2,097,152
    unsigned short* xq_bf  = (unsigned short*)d_ws;
    unsigned short* yk_bf  = xq_bf + NELEM;
    unsigned short* ykT_bf = yk_bf + NELEM;
    float* part = (float*)(ykT_bf + NELEM);

    proj_kernel<<<(int)(NBATCH * HWSZ / 64), 256, 0, stream>>>(
        x, y, W1, b1, W2, b2, out, xq_bf, yk_bf, ykT_bf);

    if (ws_size >= NELEM * (6 + 16)) {               // 46.1 MB: QBLK=128, 4-split
        attn128_kernel<<<512, 256, 0, stream>>>(xq_bf, yk_bf, ykT_bf, part);
        reduceN_kernel<4><<<(int)(NELEM / 1024), 256, 0, stream>>>(part, out);
    } else if (ws_size >= NELEM * (6 + 8)) {         // 29.4 MB: QBLK=64, 2-split
        attn_kernel<true><<<512, 256, 0, stream>>>(xq_bf, yk_bf, ykT_bf, out, part);
        reduce2_kernel<<<(int)(NELEM / 1024), 256, 0, stream>>>(part, part + NELEM, out);
    } else {
        attn_kernel<false><<<256, 256, 0, stream>>>(xq_bf, yk_bf, ykT_bf, out, out);
    }
}